// Round 1
// baseline (484.063 us; speedup 1.0000x reference)
//
#include <hip/hip_runtime.h>
#include <math.h>

#define N_ 1024
#define ROWS_PER_DIR 65536   // B*N = 64*1024
#define TOTAL_ROWS   131072  // 2 directions
#define ROWS_PER_WAVE 8      // one wave now owns the 8 rows a block used to own
#define WAVES_PER_BLOCK 8
#define VBLOCKS      (TOTAL_ROWS / ROWS_PER_WAVE)     // 16384 (same partials layout as before)
#define BLOCKS_K1    (VBLOCKS / WAVES_PER_BLOCK)      // 2048 blocks
#define BLOCKS_PER_DIR (VBLOCKS / 2)                  // 8192

typedef float v4f __attribute__((ext_vector_type(4)));
typedef float v2f __attribute__((ext_vector_type(2)));

// Kernel 1 v2: one wave per 8 consecutive rows, software-pipelined 1-deep.
// While row k's shuffle-reductions and exp work run, row k+1's four float4
// loads are already in flight -- the wave keeps outstanding VMEM for its
// whole life instead of ~half of it. Per-row math, accumulation order
// (k=0..7 == old w=0..7), and partials[vb] layout are bit-identical to the
// previously verified kernel, so the final output is bitwise unchanged.
__global__ __launch_bounds__(512) void row_loss_kernel(
    const float* __restrict__ succ_logits,
    const int*   __restrict__ succ_labels,
    const float* __restrict__ pred_logits,
    const int*   __restrict__ pred_labels,
    const int*   __restrict__ line_mask,
    v2f*         __restrict__ partials)   // [VBLOCKS] (nll_sum, valid_cnt)
{
    const int wave = threadIdx.x >> 6;
    const int lane = threadIdx.x & 63;
    const int vb   = blockIdx.x * WAVES_PER_BLOCK + wave;  // 0 .. VBLOCKS-1
    const int r0   = vb * ROWS_PER_WAVE;                   // first row of this wave
    const int dir  = r0 >> 16;                 // 0 = successor, 1 = predecessor
    const int rr0  = r0 & (ROWS_PER_DIR - 1);  // b*N + n of first row

    const float* __restrict__ logits = dir ? pred_logits : succ_logits;
    const int*   __restrict__ labels = dir ? pred_labels : succ_labels;

    // metadata for all 8 rows up front: lanes 0..7 each grab one row's
    // label+mask, broadcast later via __shfl (no per-row dependent loads)
    int lbl = 0, msk = 0;
    if (lane < ROWS_PER_WAVE) {
        lbl = labels[rr0 + lane];
        msk = line_mask[rr0 + lane];
    }

    const v4f* __restrict__ base4 = (const v4f*)(logits + (size_t)rr0 * N_);

    // preload row 0 (4 coalesced nontemporal float4 = 4 KiB/wave)
    v4f a0 = __builtin_nontemporal_load(base4 + 0 * 64 + lane);
    v4f a1 = __builtin_nontemporal_load(base4 + 1 * 64 + lane);
    v4f a2 = __builtin_nontemporal_load(base4 + 2 * 64 + lane);
    v4f a3 = __builtin_nontemporal_load(base4 + 3 * 64 + lane);

    float acc = 0.0f, cnt = 0.0f;

    #pragma unroll
    for (int k = 0; k < ROWS_PER_WAVE; ++k) {
        // issue next row's loads BEFORE touching this row's data
        v4f b0, b1, b2, b3;
        if (k < ROWS_PER_WAVE - 1) {
            const v4f* nb = base4 + (size_t)(k + 1) * 256;
            b0 = __builtin_nontemporal_load(nb + 0 * 64 + lane);
            b1 = __builtin_nontemporal_load(nb + 1 * 64 + lane);
            b2 = __builtin_nontemporal_load(nb + 2 * 64 + lane);
            b3 = __builtin_nontemporal_load(nb + 3 * 64 + lane);
        }

        const int label = __shfl(lbl, k);
        const int valid = __shfl(msk, k);
        const int n     = (rr0 + k) & (N_ - 1);

        // target index: diagonal if self-pointing, else clamped label
        const int t      = (label == -1) ? n : (label < 0 ? 0 : (label > N_ - 1 ? N_ - 1 : label));
        const int t_lane = (t >> 2) & 63;
        const int t_k    = t >> 8;
        const int t_c    = t & 3;
        v4f tv = (t_k == 0) ? a0 : (t_k == 1) ? a1 : (t_k == 2) ? a2 : a3;
        const float x_t = __shfl(tv[t_c], t_lane);   // row[t], wave-uniform

        // phase 1: row max (identical op order to verified kernel)
        float m;
        {
            v4f a = a0, b = a1;
            a.x = fmaxf(a.x, b.x); a.y = fmaxf(a.y, b.y); a.z = fmaxf(a.z, b.z); a.w = fmaxf(a.w, b.w);
            v4f c = a2; b = a3;
            c.x = fmaxf(c.x, b.x); c.y = fmaxf(c.y, b.y); c.z = fmaxf(c.z, b.z); c.w = fmaxf(c.w, b.w);
            a.x = fmaxf(a.x, c.x); a.y = fmaxf(a.y, c.y); a.z = fmaxf(a.z, c.z); a.w = fmaxf(a.w, c.w);
            m = fmaxf(fmaxf(a.x, a.y), fmaxf(a.z, a.w));
        }
        #pragma unroll
        for (int off = 32; off > 0; off >>= 1)
            m = fmaxf(m, __shfl_xor(m, off));

        // phase 2: sum of exp(x - m) at the global row max (identical order)
        float s = 0.0f;
        s += __expf(a0.x - m); s += __expf(a0.y - m); s += __expf(a0.z - m); s += __expf(a0.w - m);
        s += __expf(a1.x - m); s += __expf(a1.y - m); s += __expf(a1.z - m); s += __expf(a1.w - m);
        s += __expf(a2.x - m); s += __expf(a2.y - m); s += __expf(a2.z - m); s += __expf(a2.w - m);
        s += __expf(a3.x - m); s += __expf(a3.y - m); s += __expf(a3.z - m); s += __expf(a3.w - m);
        #pragma unroll
        for (int off = 32; off > 0; off >>= 1)
            s += __shfl_xor(s, off);

        // butterfly leaves identical values in all lanes -> compute nll on
        // all lanes (same bits as old lane-0 path)
        float nll = 0.0f;
        if (valid) {
            if (label == -1) {
                // diag overwritten with row_max+1, target = diag:
                // nll = log( e^{-1} * (s - e^{d-m}) + 1 ),  d = row[n] = x_t
                nll = __logf((s - __expf(x_t - m)) * 0.36787944117144233f + 1.0f);
            } else {
                nll = m + __logf(s) - x_t;
            }
        }
        acc += nll;                                        // same order as old w=0..7
        cnt += (dir == 0 && valid) ? 1.0f : 0.0f;

        if (k < ROWS_PER_WAVE - 1) { a0 = b0; a1 = b1; a2 = b2; a3 = b3; }
    }

    if (lane == 0) {
        v2f p; p.x = acc; p.y = cnt;
        partials[vb] = p;   // temporal store: finalize reads from L2
    }
}

// Kernel 2: single-block deterministic finalize — unchanged (partials layout
// and values are bit-identical to the previous kernel's).
__global__ __launch_bounds__(1024) void finalize_kernel(
    const v2f*   __restrict__ partials,     // [VBLOCKS]
    const float* __restrict__ pred_weight,
    float*       __restrict__ out)
{
    const int tid = threadIdx.x;
    float ssum = 0.0f, psum = 0.0f, msum = 0.0f;
    for (int i = tid; i < BLOCKS_PER_DIR; i += 1024) {
        v2f sp = partials[i];
        v2f pp = partials[i + BLOCKS_PER_DIR];
        ssum += sp.x;
        msum += sp.y;
        psum += pp.x;
    }

    #pragma unroll
    for (int off = 32; off > 0; off >>= 1) {
        ssum += __shfl_xor(ssum, off);
        psum += __shfl_xor(psum, off);
        msum += __shfl_xor(msum, off);
    }

    __shared__ float sh[3][16];
    const int wave = tid >> 6, lane = tid & 63;
    if (lane == 0) { sh[0][wave] = ssum; sh[1][wave] = psum; sh[2][wave] = msum; }
    __syncthreads();
    if (tid == 0) {
        float S = 0.0f, P = 0.0f, M = 0.0f;
        #pragma unroll
        for (int w = 0; w < 16; ++w) { S += sh[0][w]; P += sh[1][w]; M += sh[2][w]; }
        const float denom = fmaxf(M, 1.0f);
        const float sl = S / denom, pl = P / denom;
        const float w  = pred_weight[0];
        out[0] = sl + w * pl;   // total_loss
        out[1] = sl;            // succ_loss
        out[2] = pl;            // pred_loss
        out[3] = M;             // num_valid
    }
}

extern "C" void kernel_launch(void* const* d_in, const int* in_sizes, int n_in,
                              void* d_out, int out_size, void* d_ws, size_t ws_size,
                              hipStream_t stream) {
    const float* succ_logits = (const float*)d_in[0];
    const int*   succ_labels = (const int*)  d_in[1];
    const float* pred_logits = (const float*)d_in[2];
    const int*   pred_labels = (const int*)  d_in[3];
    const int*   line_mask   = (const int*)  d_in[4];
    const float* pred_weight = (const float*)d_in[5];
    float* out      = (float*)d_out;
    v2f*   partials = (v2f*)d_ws;   // 16384 float2 = 128 KiB

    row_loss_kernel<<<BLOCKS_K1, 512, 0, stream>>>(
        succ_logits, succ_labels, pred_logits, pred_labels, line_mask, partials);
    finalize_kernel<<<1, 1024, 0, stream>>>(partials, pred_weight, out);
}